// Round 13
// baseline (334.586 us; speedup 1.0000x reference)
//
#include <hip/hip_runtime.h>
#include <hip/hip_bf16.h>

// Problem constants (fixed by the reference)
#define BB 8
#define CC 512
#define TT 4096
#define HH 8
#define DH 64
#define EPS 1e-6f

#define NROWS (BB * TT)          // 32768 flat (b,t) rows

using bf16x8 = __attribute__((ext_vector_type(8))) short;
using s16x4  = __attribute__((ext_vector_type(4))) short;
using f32x4  = __attribute__((ext_vector_type(4))) float;

__device__ __forceinline__ short f2b(float f) {
  __hip_bfloat16 h = __float2bfloat16(f);
  return *reinterpret_cast<short*>(&h);
}
__device__ __forceinline__ float b2f(short s) {
  unsigned u = ((unsigned)(unsigned short)s) << 16;
  return __uint_as_float(u);
}

// async global->LDS 16B copy (dest must be wave-uniform base + lane*16)
__device__ __forceinline__ void gld16(short* lds_dst, const short* gsrc) {
  __builtin_amdgcn_global_load_lds(
      (const __attribute__((address_space(1))) unsigned int*)gsrc,
      (__attribute__((address_space(3))) unsigned int*)lds_dst, 16, 0, 0);
}

// 4 weights fp32 [o][c] -> bf16 [o][c], one launch
__global__ __launch_bounds__(256) void conv_w4(const float* __restrict__ s0, const float* __restrict__ s1,
                                               const float* __restrict__ s2, const float* __restrict__ s3,
                                               short* __restrict__ d0, short* __restrict__ d1,
                                               short* __restrict__ d2, short* __restrict__ d3)
{
  const float* src; short* dst;
  switch (blockIdx.y) {
    case 0: src = s0; dst = d0; break;
    case 1: src = s1; dst = d1; break;
    case 2: src = s2; dst = d2; break;
    default: src = s3; dst = d3; break;
  }
  int i8 = (blockIdx.x * 256 + threadIdx.x) * 8;
  float4 a = *(const float4*)(src + i8);
  float4 b = *(const float4*)(src + i8 + 4);
  bf16x8 h = { f2b(a.x), f2b(a.y), f2b(a.z), f2b(a.w),
               f2b(b.x), f2b(b.y), f2b(b.z), f2b(b.w) };
  *(bf16x8*)(dst + i8) = h;
}

// ---------------------------------------------------------------------------
// transpose+convert (r11 variant — measured-stable ~88 us, conflict-free):
// X fp32 [b][c][t] -> Xt bf16 [b][t][c]. grid (T/256, C/64, 3*B).
// ---------------------------------------------------------------------------
#define TSTR 120
__device__ __forceinline__ int tadr(int c, int t) {
  return c * TSTR + ((c >> 3) & 7) * 8 + t;
}

__global__ __launch_bounds__(256) void transpose_cvt3(const float* __restrict__ X0,
                                                      const float* __restrict__ X1,
                                                      const float* __restrict__ X2,
                                                      short* __restrict__ Y0,
                                                      short* __restrict__ Y1,
                                                      short* __restrict__ Y2)
{
  __shared__ short tile[64 * TSTR];
  const int t0 = blockIdx.x * 256, c0 = blockIdx.y * 64;
  const int b = blockIdx.z & 7, which = blockIdx.z >> 3;
  const float* X = which == 0 ? X0 : (which == 1 ? X1 : X2);
  short* Xt = which == 0 ? Y0 : (which == 1 ? Y1 : Y2);
  const int tid = threadIdx.x;
  const int cl = tid >> 4, t4 = (tid & 15) * 4;       // phase A coords
  const int T2 = (tid >> 3) * 2, ci = (tid & 7) * 8;  // phase B coords

  float4 rc[4];
  #pragma unroll
  for (int it = 0; it < 4; ++it)
    rc[it] = *(const float4*)(X + ((size_t)b * CC + c0 + it * 16 + cl) * TT + t0 + t4);

  #pragma unroll
  for (int s = 0; s < 4; ++s) {
    float4 rn[4];
    if (s < 3) {
      #pragma unroll
      for (int it = 0; it < 4; ++it)
        rn[it] = *(const float4*)(X + ((size_t)b * CC + c0 + it * 16 + cl) * TT
                                  + t0 + (s + 1) * 64 + t4);
    }
    #pragma unroll
    for (int it = 0; it < 4; ++it) {
      s16x4 h = { f2b(rc[it].x), f2b(rc[it].y), f2b(rc[it].z), f2b(rc[it].w) };
      *(s16x4*)&tile[tadr(it * 16 + cl, t4)] = h;
    }
    asm volatile("s_waitcnt lgkmcnt(0)" ::: "memory");
    __builtin_amdgcn_s_barrier();
    __builtin_amdgcn_sched_barrier(0);
    unsigned u[8];
    #pragma unroll
    for (int i = 0; i < 8; ++i)
      u[i] = *(const unsigned*)&tile[tadr(ci + i, T2)];
    short lo[8], hi[8];
    #pragma unroll
    for (int i = 0; i < 8; ++i) {
      lo[i] = (short)(u[i] & 0xffffu);
      hi[i] = (short)(u[i] >> 16);
    }
    short* dst0 = Xt + ((size_t)b * TT + t0 + s * 64 + T2) * CC + c0 + ci;
    *(bf16x8*)dst0 = *(bf16x8*)&lo[0];
    *(bf16x8*)(dst0 + CC) = *(bf16x8*)&hi[0];
    __builtin_amdgcn_sched_barrier(0);
    __builtin_amdgcn_s_barrier();
    __builtin_amdgcn_sched_barrier(0);
    #pragma unroll
    for (int it = 0; it < 4; ++it) rc[it] = rn[it];
  }
}

// ---------------------------------------------------------------------------
// Fused GEMM + feature epilogue. One block = 128 rows x ALL 512 outs, 8 waves
// (wave w owns cols [w*64, w*64+64)). K-loop: T4 counted-vmcnt double buffer.
// Epilogue: bias -> block RMSNorm (cross-wave LDS reduce) -> elu+1 ->
//   mode 0 (Q): per-head softmax (head == wave) * 8^-0.5
//   mode 1 (K): exp (unnormalized), masked rows -> 0, atomic col-sums into S
//   mode 2 (V): /64
// writes finished bf16 features — kills feat_all + ksm_sum round trips.
// ---------------------------------------------------------------------------
__global__ __launch_bounds__(512, 2) void gemm_feat3(
    const short* __restrict__ qt, const short* __restrict__ kt, const short* __restrict__ vt,
    const short* __restrict__ wq, const short* __restrict__ wk, const short* __restrict__ wv,
    const float* __restrict__ bq, const float* __restrict__ bk, const float* __restrict__ bv,
    const float* __restrict__ gq, const float* __restrict__ gk, const float* __restrict__ gv,
    const unsigned char* __restrict__ mask, float* __restrict__ S,
    short* __restrict__ qf, short* __restrict__ kf, short* __restrict__ vf)
{
  __shared__ short As[2][128 * 32];    // 16 KB
  __shared__ short Ws[2][512 * 32];    // 64 KB
  const int mode = blockIdx.y;
  const short* A = mode == 0 ? qt : (mode == 1 ? kt : vt);
  const short* W = mode == 0 ? wq : (mode == 1 ? wk : wv);
  const float* bias = mode == 0 ? bq : (mode == 1 ? bk : bv);
  const float* g = mode == 0 ? gq : (mode == 1 ? gk : gv);
  short* Y = mode == 0 ? qf : (mode == 1 ? kf : vf);

  const int m0 = blockIdx.x * 128;
  const int tid = threadIdx.x;
  const int w = tid >> 6, lane = tid & 63;
  const int lr = lane & 15, lg = lane >> 4;
  const int swz8 = (lg ^ ((lr >> 1) & 3)) * 8;   // read-side swizzle
  const int arow = tid >> 2, ach = tid & 3;
  const int ascol = (ach ^ ((arow >> 1) & 3)) * 8;

  f32x4 acc[8][4] = {};

  // prologue: stage step 0 (1 A-chunk + 4 W-chunks per thread)
  gld16(&As[0][tid * 8], A + (size_t)(m0 + arow) * CC + ascol);
  #pragma unroll
  for (int it = 0; it < 4; ++it) {
    int slot = it * 512 + tid;
    int wrow = slot >> 2, wch = slot & 3;
    gld16(&Ws[0][slot * 8], W + (size_t)wrow * CC + ((wch ^ ((wrow >> 1) & 3)) * 8));
  }

  for (int step = 0; step < 16; ++step) {
    const int cur = step & 1;
    if (step < 15) {
      const int k0 = (step + 1) * 32;
      gld16(&As[cur ^ 1][tid * 8], A + (size_t)(m0 + arow) * CC + k0 + ascol);
      #pragma unroll
      for (int it = 0; it < 4; ++it) {
        int slot = it * 512 + tid;
        int wrow = slot >> 2, wch = slot & 3;
        gld16(&Ws[cur ^ 1][slot * 8], W + (size_t)wrow * CC + k0 + ((wch ^ ((wrow >> 1) & 3)) * 8));
      }
      asm volatile("s_waitcnt vmcnt(5)" ::: "memory");   // cur-buf loads done
    } else {
      asm volatile("s_waitcnt vmcnt(0)" ::: "memory");
    }
    __builtin_amdgcn_s_barrier();
    __builtin_amdgcn_sched_barrier(0);

    bf16x8 af[8];
    #pragma unroll
    for (int mf = 0; mf < 8; ++mf)
      af[mf] = *(const bf16x8*)&As[cur][(mf * 16 + lr) * 32 + swz8];
    #pragma unroll
    for (int nf = 0; nf < 4; ++nf) {
      bf16x8 bfv = *(const bf16x8*)&Ws[cur][(w * 64 + nf * 16 + lr) * 32 + swz8];
      #pragma unroll
      for (int mf = 0; mf < 8; ++mf)
        acc[mf][nf] = __builtin_amdgcn_mfma_f32_16x16x32_bf16(af[mf], bfv, acc[mf][nf], 0, 0, 0);
    }
    __builtin_amdgcn_sched_barrier(0);
    __builtin_amdgcn_s_barrier();
    __builtin_amdgcn_sched_barrier(0);
  }

  // ---------------- fused feature epilogue ----------------
  float* ssb  = (float*)&As[0][0];     // [8][128] partial sum-of-squares
  float* rmsb = ssb + 1024;            // [128] rsqrt values
  const int b = m0 >> 12;              // batch (blocks never straddle b)

  float bcol[4], gcol[4];
  #pragma unroll
  for (int nf = 0; nf < 4; ++nf) {
    int col = w * 64 + nf * 16 + lr;
    bcol[nf] = bias[col];
    gcol[nf] = g[col];
  }

  // bias add + per-row partial sum of squares (this wave's 64 cols)
  #pragma unroll
  for (int mf = 0; mf < 8; ++mf) {
    #pragma unroll
    for (int r = 0; r < 4; ++r) {
      float p = 0.f;
      #pragma unroll
      for (int nf = 0; nf < 4; ++nf) {
        float v = acc[mf][nf][r] + bcol[nf];
        acc[mf][nf][r] = v;
        p += v * v;
      }
      p += __shfl_xor(p, 1); p += __shfl_xor(p, 2);
      p += __shfl_xor(p, 4); p += __shfl_xor(p, 8);
      if (lr == 0) ssb[w * 128 + mf * 16 + lg * 4 + r] = p;
    }
  }
  __syncthreads();
  if (tid < 128) {
    float tot = 0.f;
    #pragma unroll
    for (int ww = 0; ww < 8; ++ww) tot += ssb[ww * 128 + tid];
    rmsb[tid] = rsqrtf(tot * (1.0f / CC) + EPS);
  }
  __syncthreads();

  if (mode == 2) {           // V: elu+1 then /64
    #pragma unroll
    for (int mf = 0; mf < 8; ++mf)
      #pragma unroll
      for (int r = 0; r < 4; ++r) {
        int rl = mf * 16 + lg * 4 + r;
        float rn = rmsb[rl];
        size_t rowoff = (size_t)(m0 + rl) * CC;
        #pragma unroll
        for (int nf = 0; nf < 4; ++nf) {
          float x = acc[mf][nf][r] * rn * gcol[nf];
          float f = x > 0.f ? x + 1.f : __expf(x);
          Y[rowoff + w * 64 + nf * 16 + lr] = f2b(f * (1.0f / DH));
        }
      }
  } else if (mode == 1) {    // K: exp(elu+1), mask -> 0, col-sum atomics
    float ks[4] = { 0.f, 0.f, 0.f, 0.f };
    #pragma unroll
    for (int mf = 0; mf < 8; ++mf)
      #pragma unroll
      for (int r = 0; r < 4; ++r) {
        int rl = mf * 16 + lg * 4 + r;
        float rn = rmsb[rl];
        bool mk = mask[m0 + rl] != 0;
        size_t rowoff = (size_t)(m0 + rl) * CC;
        #pragma unroll
        for (int nf = 0; nf < 4; ++nf) {
          float x = acc[mf][nf][r] * rn * gcol[nf];
          float f = x > 0.f ? x + 1.f : __expf(x);
          float e = mk ? 0.f : __expf(f);
          ks[nf] += e;
          Y[rowoff + w * 64 + nf * 16 + lr] = f2b(e);
        }
      }
    #pragma unroll
    for (int nf = 0; nf < 4; ++nf) {
      ks[nf] += __shfl_xor(ks[nf], 16);
      ks[nf] += __shfl_xor(ks[nf], 32);
    }
    if (lane < 16) {
      #pragma unroll
      for (int nf = 0; nf < 4; ++nf)
        atomicAdd(&S[b * CC + w * 64 + nf * 16 + lr], ks[nf]);
    }
  } else {                   // Q: softmax over this head's 64 cols (head == w)
    #pragma unroll
    for (int mf = 0; mf < 8; ++mf)
      #pragma unroll
      for (int r = 0; r < 4; ++r) {
        int rl = mf * 16 + lg * 4 + r;
        float rn = rmsb[rl];
        float es[4]; float qs = 0.f;
        #pragma unroll
        for (int nf = 0; nf < 4; ++nf) {
          float x = acc[mf][nf][r] * rn * gcol[nf];
          float f = x > 0.f ? x + 1.f : __expf(x);
          float e = __expf(f);                 // no max-sub: f <= ~24, safe
          es[nf] = e; qs += e;
        }
        qs += __shfl_xor(qs, 1); qs += __shfl_xor(qs, 2);
        qs += __shfl_xor(qs, 4); qs += __shfl_xor(qs, 8);
        float sc = 0.35355339059327373f / qs;  // 8^-0.5 / sum
        size_t rowoff = (size_t)(m0 + rl) * CC;
        #pragma unroll
        for (int nf = 0; nf < 4; ++nf)
          Y[rowoff + w * 64 + nf * 16 + lr] = f2b(es[nf] * sc);
      }
  }
}

// ---------------------------------------------------------------------------
// proj GEMM (unchanged): Y[m][o] = sum_c A[m][c] * W[o][c] + bias[o].
// 128x128, BK=32, T4 counted vmcnt, both-sides XOR swizzle.
// ---------------------------------------------------------------------------
__global__ __launch_bounds__(256) void gemm_tc(const short* __restrict__ A,
                                               const short* __restrict__ W,
                                               const float* __restrict__ bias,
                                               short* __restrict__ Y)
{
  __shared__ short As[2 * 4096];
  __shared__ short Bs[2 * 4096];
  const int tid = threadIdx.x;
  int x = blockIdx.x;
  int wg = (x & 7) * 128 + (x >> 3);       // XCD-chunked
  const int m0 = (wg >> 2) * 128;
  const int o0 = (wg & 3) * 128;

  const int wid = tid >> 6, lane = tid & 63;
  const int wr = (wid >> 1) * 64, wc = (wid & 1) * 64;
  const int lr = lane & 15, g = lane >> 4;
  const int swz8 = (g ^ ((lr >> 1) & 3)) * 8;
  const int srow0 = tid >> 2;
  const int scol  = ((tid & 3) ^ ((tid >> 3) & 3)) * 8;

  f32x4 acc[4][4] = {};

  #pragma unroll
  for (int it = 0; it < 2; ++it) {
    int row = it * 64 + srow0;
    gld16(&As[it * 2048 + tid * 8], A + (size_t)(m0 + row) * CC + scol);
    gld16(&Bs[it * 2048 + tid * 8], W + (size_t)(o0 + row) * CC + scol);
  }

  for (int step = 0; step < 16; ++step) {
    const int cur = step & 1;
    if (step < 15) {
      const int k0 = (step + 1) * 32;
      #pragma unroll
      for (int it = 0; it < 2; ++it) {
        int row = it * 64 + srow0;
        gld16(&As[(cur ^ 1) * 4096 + it * 2048 + tid * 8], A + (size_t)(m0 + row) * CC + k0 + scol);
        gld16(&Bs[(cur ^ 1) * 4096 + it * 2048 + tid * 8], W + (size_t)(o0 + row) * CC + k0 + scol);
      }
      asm volatile("s_waitcnt vmcnt(4)" ::: "memory");
    } else {
      asm volatile("s_waitcnt vmcnt(0)" ::: "memory");
    }
    __builtin_amdgcn_s_barrier();
    __builtin_amdgcn_sched_barrier(0);

    bf16x8 af[4], bf[4];
    #pragma unroll
    for (int m = 0; m < 4; ++m) af[m] = *(const bf16x8*)&As[cur * 4096 + (wr + m * 16 + lr) * 32 + swz8];
    #pragma unroll
    for (int n = 0; n < 4; ++n) bf[n] = *(const bf16x8*)&Bs[cur * 4096 + (wc + n * 16 + lr) * 32 + swz8];
    #pragma unroll
    for (int m = 0; m < 4; ++m)
      #pragma unroll
      for (int n = 0; n < 4; ++n)
        acc[m][n] = __builtin_amdgcn_mfma_f32_16x16x32_bf16(af[m], bf[n], acc[m][n], 0, 0, 0);

    __builtin_amdgcn_sched_barrier(0);
    __builtin_amdgcn_s_barrier();
    __builtin_amdgcn_sched_barrier(0);
  }

  const int lq4 = (lane >> 4) * 4;
  #pragma unroll
  for (int m = 0; m < 4; ++m)
    #pragma unroll
    for (int r = 0; r < 4; ++r) {
      size_t row = (size_t)(m0 + wr + m * 16 + lq4 + r) * CC;
      #pragma unroll
      for (int n = 0; n < 4; ++n) {
        int o = o0 + wc + n * 16 + lr;
        Y[row + o] = f2b(acc[m][n][r] + bias[o]);
      }
    }
}

// ---------------------------------------------------------------------------
// ctx partials from t-major kfe/vf: P[tc][bh][q][v] = sum_t kfe[t][q]*vf[t][v]
// ---------------------------------------------------------------------------
__global__ __launch_bounds__(256) void ctx_t(const short* __restrict__ kf,
                                             const short* __restrict__ vf,
                                             float* __restrict__ P)
{
  __shared__ short Ks[64 * 64];
  __shared__ short Vs[64 * 64];
  const int tc = blockIdx.x, bh = blockIdx.y;
  const int b = bh >> 3, h = bh & 7;
  const int tid = threadIdx.x, wid = tid >> 6, lane = tid & 63;
  const int lr = lane & 15, lg = lane >> 4;
  f32x4 acc[4] = {};

  for (int ts = 0; ts < 8; ++ts) {
    #pragma unroll
    for (int i = 0; i < 2; ++i) {
      int n = i * 256 + tid;
      int t = n >> 3, ch = (n & 7) * 8;
      size_t src = ((size_t)b * TT + tc * 512 + ts * 64 + t) * CC + h * DH + ch;
      gld16(Ks + n * 8, kf + src);
      gld16(Vs + n * 8, vf + src);
    }
    __syncthreads();
    #pragma unroll
    for (int kk = 0; kk < 64; kk += 32) {
      short a[8];
      #pragma unroll
      for (int j = 0; j < 8; ++j)
        a[j] = Ks[(kk + lg * 8 + j) * 64 + wid * 16 + lr];
      bf16x8 af = *(const bf16x8*)&a[0];
      #pragma unroll
      for (int n = 0; n < 4; ++n) {
        short bv[8];
        #pragma unroll
        for (int j = 0; j < 8; ++j)
          bv[j] = Vs[(kk + lg * 8 + j) * 64 + n * 16 + lr];
        acc[n] = __builtin_amdgcn_mfma_f32_16x16x32_bf16(af, *(const bf16x8*)&bv[0],
                                                         acc[n], 0, 0, 0);
      }
    }
    __syncthreads();
  }
  float* pp = P + ((size_t)tc * 64 + bh) * (DH * DH);
  const int lq4 = lg * 4;
  #pragma unroll
  for (int n = 0; n < 4; ++n)
    #pragma unroll
    for (int r = 0; r < 4; ++r)
      pp[(wid * 16 + lq4 + r) * DH + n * 16 + lr] = acc[n][r];
}

// reduce chunk partials, apply 1/S (deferred k-softmax norm), emit CT[bh][v][q]
__global__ __launch_bounds__(256) void ctx_reduce(const float* __restrict__ P,
                                                  const float* __restrict__ S,
                                                  short* __restrict__ CT)
{
  int i = blockIdx.x * 256 + threadIdx.x;    // (bh, q, v), v fastest
  float s = 0.f;
  #pragma unroll
  for (int c = 0; c < 8; ++c) s += P[(size_t)c * 64 * DH * DH + i];
  int bh = i >> 12, rem = i & 4095, q = rem >> 6, v = rem & 63;
  int b = bh >> 3, h = bh & 7;
  float inv = 1.f / S[b * CC + h * DH + q];
  CT[((size_t)bh << 12) + v * 64 + q] = f2b(s * inv);
}

// ---------------------------------------------------------------------------
// attn: ao[row][h*64+v] = sum_q qf[row][h*64+q] * CT[bh][v][q]
// ---------------------------------------------------------------------------
__global__ __launch_bounds__(256) void attn_t(const short* __restrict__ qf,
                                              const short* __restrict__ CT,
                                              short* __restrict__ ao)
{
  __shared__ short As[128 * 72];
  __shared__ short Cs[64 * 72];
  const int m0 = blockIdx.x * 128, h = blockIdx.y;
  const int tid = threadIdx.x, wid = tid >> 6, lane = tid & 63;
  const int lr = lane & 15, lk8 = (lane >> 4) * 8;

  #pragma unroll
  for (int i = 0; i < 4; ++i) {
    int n = i * 256 + tid;
    int r = n >> 3, ch = (n & 7) * 8;
    *(bf16x8*)&As[r * 72 + ch] =
        *(const bf16x8*)(qf + (size_t)(m0 + r) * CC + h * DH + ch);
  }
  {
    const int bh0 = (m0 / TT) * 8 + h;
    #pragma unroll
    for (int i = 0; i < 2; ++i) {
      int n = i * 256 + tid;
      int v = n >> 3, ch = (n & 7) * 8;
      *(bf16x8*)&Cs[v * 72 + ch] = *(const bf16x8*)(CT + ((size_t)bh0 << 12) + v * 64 + ch);
    }
  }
  __syncthreads();

  const int wr = wid * 32;
  f32x4 acc[2][4] = {};
  #pragma unroll
  for (int kk = 0; kk < 64; kk += 32) {
    bf16x8 af[2], cf[4];
    #pragma unroll
    for (int m = 0; m < 2; ++m) af[m] = *(const bf16x8*)&As[(wr + m * 16 + lr) * 72 + kk + lk8];
    #pragma unroll
    for (int n = 0; n < 4; ++n) cf[n] = *(const bf16x8*)&Cs[(n * 16 + lr) * 72 + kk + lk8];
    #pragma unroll
    for (int m = 0; m < 2; ++m)
      #pragma unroll
      for (int n = 0; n < 4; ++n)
        acc[m][n] = __builtin_amdgcn_mfma_f32_16x16x32_bf16(af[m], cf[n], acc[m][n], 0, 0, 0);
  }
  const int lq4 = (lane >> 4) * 4;
  #pragma unroll
  for (int m = 0; m < 2; ++m)
    #pragma unroll
    for (int r = 0; r < 4; ++r) {
      size_t row = (size_t)(m0 + wr + m * 16 + lq4 + r) * CC + h * DH;
      #pragma unroll
      for (int n = 0; n < 4; ++n)
        ao[row + n * 16 + lr] = f2b(acc[m][n][r]);
    }
}

// ---------------------------------------------------------------------------
// fused final: single global read. Pass1 computes rms AND stores z=pj+qt
// as bf16 into LDS z[c][t] (stride 72). Pass2 reads z rows (b128), scales by
// rms[t]*g[c], coalesced float4 stores to [c][t].
// ---------------------------------------------------------------------------
__global__ __launch_bounds__(256) void final_fused(const short* __restrict__ pj,
                                                   const short* __restrict__ qt,
                                                   const float* __restrict__ g,
                                                   float* __restrict__ out)
{
  __shared__ short z[512 * 72];            // 72 KB
  __shared__ float rmss[64];
  const int t0 = blockIdx.x * 64, b = blockIdx.y;
  const int tid = threadIdx.x;

  {
    const int t = tid >> 2, cb = (tid & 3) * 128;
    const size_t row = ((size_t)b * TT + t0 + t) * CC + cb;
    float ss = 0.f;
    #pragma unroll
    for (int j = 0; j < 16; ++j) {
      bf16x8 a = *(const bf16x8*)(pj + row + j * 8);
      bf16x8 q = *(const bf16x8*)(qt + row + j * 8);
      #pragma unroll
      for (int e = 0; e < 8; ++e) {
        float zf = b2f(a[e]) + b2f(q[e]);
        ss += zf * zf;
        z[(cb + j * 8 + e) * 72 + t] = f2b(zf);
      }
    }
    ss += __shfl_xor(ss, 1);
    ss += __shfl_xor(ss, 2);
    if ((tid & 3) == 0) rmss[t] = rsqrtf(ss * (1.0f / CC) + EPS);
  }
  __syncthreads();

  const int c = tid >> 2, tcs = (tid & 3) * 16;
  #pragma unroll 1
  for (int cb8 = 0; cb8 < 8; ++cb8) {
    const int cc = cb8 * 64 + c;
    const float gc = g[cc];
    bf16x8 z0 = *(const bf16x8*)&z[cc * 72 + tcs];
    bf16x8 z1 = *(const bf16x8*)&z[cc * 72 + tcs + 8];
    float* dst = out + ((size_t)b * CC + cc) * TT + t0 + tcs;
    #pragma unroll
    for (int i = 0; i < 2; ++i) {
      float4 o0 = { b2f(z0[i*4+0]) * rmss[tcs+i*4+0] * gc, b2f(z0[i*4+1]) * rmss[tcs+i*4+1] * gc,
                    b2f(z0[i*4+2]) * rmss[tcs+i*4+2] * gc, b2f(z0[i*4+3]) * rmss[tcs+i*4+3] * gc };
      *(float4*)(dst + i * 4) = o0;
    }
    #pragma unroll
    for (int i = 0; i < 2; ++i) {
      float4 o1 = { b2f(z1[i*4+0]) * rmss[tcs+8+i*4+0] * gc, b2f(z1[i*4+1]) * rmss[tcs+8+i*4+1] * gc,
                    b2f(z1[i*4+2]) * rmss[tcs+8+i*4+2] * gc, b2f(z1[i*4+3]) * rmss[tcs+8+i*4+3] * gc };
      *(float4*)(dst + 8 + i * 4) = o1;
    }
  }
}

// ---------------------------------------------------------------------------
extern "C" void kernel_launch(void* const* d_in, const int* in_sizes, int n_in,
                              void* d_out, int out_size, void* d_ws, size_t ws_size,
                              hipStream_t stream) {
  (void)in_sizes; (void)n_in; (void)out_size; (void)ws_size;
  const float* queries = (const float*)d_in[0];
  const float* keys    = (const float*)d_in[1];
  const float* values  = (const float*)d_in[2];
  const unsigned char* mask = (const unsigned char*)d_in[3];
  const float* Wq = (const float*)d_in[4];
  const float* bq = (const float*)d_in[5];
  const float* gq = (const float*)d_in[6];
  const float* Wk = (const float*)d_in[7];
  const float* bk = (const float*)d_in[8];
  const float* gk = (const float*)d_in[9];
  const float* Wv = (const float*)d_in[10];
  const float* bv = (const float*)d_in[11];
  const float* gv = (const float*)d_in[12];
  const float* Wp = (const float*)d_in[13];
  const float* bp = (const float*)d_in[14];
  const float* g_out = (const float*)d_in[15];

  const size_t NCT = (size_t)NROWS * CC;       // 16,777,216 elements
  short* qt = (short*)d_ws;                    // bf16 [row][c] transposed inputs
  short* kt = qt + NCT;
  short* vt = kt + NCT;
  short* qf = vt + NCT;                        // feature outputs
  short* kf = qf + NCT;
  short* vf = kf + NCT;
  short* ao = kt;                              // reuse (kt dead after gemm_feat3)
  short* pj = vt;                              // reuse (vt dead after gemm_feat3)
  float* ctxP = (float*)(vf + NCT);            // 8 x 64 x 4096 fp32
  short* CT  = (short*)(ctxP + (size_t)8 * 64 * DH * DH);   // [bh][v][q] bf16
  short* wqb = CT + (size_t)64 * DH * DH;
  short* wkb = wqb + (size_t)CC * CC;
  short* wvb = wkb + (size_t)CC * CC;
  short* wpb = wvb + (size_t)CC * CC;
  float* S   = (float*)(wpb + (size_t)CC * CC);   // [B][C] softmax sums

  hipMemsetAsync(S, 0, (size_t)BB * CC * sizeof(float), stream);

  conv_w4<<<dim3(CC * CC / 2048, 4), 256, 0, stream>>>(Wq, Wk, Wv, Wp, wqb, wkb, wvb, wpb);

  transpose_cvt3<<<dim3(TT / 256, CC / 64, 3 * BB), 256, 0, stream>>>(
      queries, keys, values, qt, kt, vt);

  gemm_feat3<<<dim3(NROWS / 128, 3), 512, 0, stream>>>(
      qt, kt, vt, wqb, wkb, wvb, bq, bk, bv, gq, gk, gv, mask, S, qf, kf, vf);

  ctx_t<<<dim3(8, BB * HH), 256, 0, stream>>>(kf, vf, ctxP);
  ctx_reduce<<<dim3(64 * DH * DH / 256), 256, 0, stream>>>(ctxP, S, CT);

  attn_t<<<dim3(NROWS / 128, HH), 256, 0, stream>>>(qf, CT, ao);

  gemm_tc<<<dim3(1024), 256, 0, stream>>>(ao, wpb, bp, pj);

  final_fused<<<dim3(TT / 64, BB), 256, 0, stream>>>(pj, qt, g_out, (float*)d_out);
}

// Round 14
// 323.413 us; speedup vs baseline: 1.0345x; 1.0345x over previous
//
#include <hip/hip_runtime.h>
#include <hip/hip_bf16.h>

// Problem constants (fixed by the reference)
#define BB 8
#define CC 512
#define TT 4096
#define HH 8
#define DH 64
#define EPS 1e-6f

#define NROWS (BB * TT)          // 32768 flat (b,t) rows

using bf16x8 = __attribute__((ext_vector_type(8))) short;
using s16x4  = __attribute__((ext_vector_type(4))) short;
using f32x4  = __attribute__((ext_vector_type(4))) float;

__device__ __forceinline__ short f2b(float f) {
  __hip_bfloat16 h = __float2bfloat16(f);
  return *reinterpret_cast<short*>(&h);
}
__device__ __forceinline__ float b2f(short s) {
  unsigned u = ((unsigned)(unsigned short)s) << 16;
  return __uint_as_float(u);
}

// async global->LDS 16B copy (dest must be wave-uniform base + lane*16)
__device__ __forceinline__ void gld16(short* lds_dst, const short* gsrc) {
  __builtin_amdgcn_global_load_lds(
      (const __attribute__((address_space(1))) unsigned int*)gsrc,
      (__attribute__((address_space(3))) unsigned int*)lds_dst, 16, 0, 0);
}

// 4 weights fp32 [o][c] -> bf16 [o][c], one launch
__global__ __launch_bounds__(256) void conv_w4(const float* __restrict__ s0, const float* __restrict__ s1,
                                               const float* __restrict__ s2, const float* __restrict__ s3,
                                               short* __restrict__ d0, short* __restrict__ d1,
                                               short* __restrict__ d2, short* __restrict__ d3)
{
  const float* src; short* dst;
  switch (blockIdx.y) {
    case 0: src = s0; dst = d0; break;
    case 1: src = s1; dst = d1; break;
    case 2: src = s2; dst = d2; break;
    default: src = s3; dst = d3; break;
  }
  int i8 = (blockIdx.x * 256 + threadIdx.x) * 8;
  float4 a = *(const float4*)(src + i8);
  float4 b = *(const float4*)(src + i8 + 4);
  bf16x8 h = { f2b(a.x), f2b(a.y), f2b(a.z), f2b(a.w),
               f2b(b.x), f2b(b.y), f2b(b.z), f2b(b.w) };
  *(bf16x8*)(dst + i8) = h;
}

// ---------------------------------------------------------------------------
// transpose+convert (r10 best-measured variant): X fp32 [b][c][t] -> bf16
// [b][t][c]. grid (T/256, C/64, 3*B); 4 sub-tiles of 64t x 64c, double-
// buffered LDS, prefetch before the single barrier. Stride 120 + pad(c):
// phase-B gather <=2-way; phase-B reads b32 pairs -> 2 output rows/thread.
// ---------------------------------------------------------------------------
#define TSTR 120
__device__ __forceinline__ int tadr(int c, int t) {
  return c * TSTR + ((c >> 3) & 7) * 8 + t;
}

__global__ __launch_bounds__(256) void transpose_cvt3(const float* __restrict__ X0,
                                                      const float* __restrict__ X1,
                                                      const float* __restrict__ X2,
                                                      short* __restrict__ Y0,
                                                      short* __restrict__ Y1,
                                                      short* __restrict__ Y2)
{
  __shared__ short tile[2][64 * TSTR];
  const int t0 = blockIdx.x * 256, c0 = blockIdx.y * 64;
  const int b = blockIdx.z & 7, which = blockIdx.z >> 3;
  const float* X = which == 0 ? X0 : (which == 1 ? X1 : X2);
  short* Xt = which == 0 ? Y0 : (which == 1 ? Y1 : Y2);
  const int tid = threadIdx.x;
  const int cl = tid >> 4, t4 = (tid & 15) * 4;       // phase A coords
  const int T2 = (tid >> 3) * 2, ci = (tid & 7) * 8;  // phase B coords

  float4 r[4];
  #pragma unroll
  for (int it = 0; it < 4; ++it)
    r[it] = *(const float4*)(X + ((size_t)b * CC + c0 + it * 16 + cl) * TT + t0 + t4);

  for (int s = 0; s < 4; ++s) {
    const int cur = s & 1;
    #pragma unroll
    for (int it = 0; it < 4; ++it) {
      s16x4 h = { f2b(r[it].x), f2b(r[it].y), f2b(r[it].z), f2b(r[it].w) };
      *(s16x4*)&tile[cur][tadr(it * 16 + cl, t4)] = h;
    }
    if (s < 3) {
      #pragma unroll
      for (int it = 0; it < 4; ++it)
        r[it] = *(const float4*)(X + ((size_t)b * CC + c0 + it * 16 + cl) * TT
                                 + t0 + (s + 1) * 64 + t4);
    }
    __syncthreads();
    unsigned u[8];
    #pragma unroll
    for (int i = 0; i < 8; ++i)
      u[i] = *(const unsigned*)&tile[cur][tadr(ci + i, T2)];
    short lo[8], hi[8];
    #pragma unroll
    for (int i = 0; i < 8; ++i) {
      lo[i] = (short)(u[i] & 0xffffu);
      hi[i] = (short)(u[i] >> 16);
    }
    short* dst0 = Xt + ((size_t)b * TT + t0 + s * 64 + T2) * CC + c0 + ci;
    *(bf16x8*)dst0 = *(bf16x8*)&lo[0];
    *(bf16x8*)(dst0 + CC) = *(bf16x8*)&hi[0];
    // single barrier per sub-tile is safe: this thread's reads of buffer
    // cur completed before its global store, which precedes the next
    // barrier; next iteration writes buffer cur^1.
  }
}

// ---------------------------------------------------------------------------
// GEMM body (r10 measured-best): Y[m][o] = sum_c A[m][c]*W[o][c] + bias[o].
// 128x128, BK=32, double-buffered LDS, both-sides XOR swizzle, gld16 staging.
// ---------------------------------------------------------------------------
__device__ __forceinline__ void gemm_body(const short* __restrict__ A,
                                          const short* __restrict__ W,
                                          const float* __restrict__ bias,
                                          short* __restrict__ Y,
                                          short* As, short* Bs, int x, int tid)
{
  int wg = (x & 7) * 128 + (x >> 3);       // XCD-chunked
  const int m0 = (wg >> 2) * 128;          // 256 m-tiles
  const int o0 = (wg & 3) * 128;           // 4 o-tiles

  const int wid = tid >> 6, lane = tid & 63;
  const int wr = (wid >> 1) * 64, wc = (wid & 1) * 64;
  const int lr = lane & 15, g = lane >> 4;
  const int swz8 = (g ^ ((lr >> 1) & 3)) * 8;           // read-side swizzle

  const int srow0 = tid >> 2;                            // + it*64
  const int scol  = ((tid & 3) ^ ((tid >> 3) & 3)) * 8;  // source-side swizzle

  f32x4 acc[4][4] = {};

  #pragma unroll
  for (int it = 0; it < 2; ++it) {
    int row = it * 64 + srow0;
    gld16(&As[it * 2048 + tid * 8], A + (size_t)(m0 + row) * CC + scol);
    gld16(&Bs[it * 2048 + tid * 8], W + (size_t)(o0 + row) * CC + scol);
  }
  __syncthreads();

  for (int step = 0; step < 16; ++step) {
    const int cur = step & 1;
    if (step < 15) {
      const int k0 = (step + 1) * 32;
      #pragma unroll
      for (int it = 0; it < 2; ++it) {
        int row = it * 64 + srow0;
        gld16(&As[(cur ^ 1) * 4096 + it * 2048 + tid * 8], A + (size_t)(m0 + row) * CC + k0 + scol);
        gld16(&Bs[(cur ^ 1) * 4096 + it * 2048 + tid * 8], W + (size_t)(o0 + row) * CC + k0 + scol);
      }
    }
    bf16x8 af[4], bf[4];
    #pragma unroll
    for (int m = 0; m < 4; ++m) af[m] = *(const bf16x8*)&As[cur * 4096 + (wr + m * 16 + lr) * 32 + swz8];
    #pragma unroll
    for (int n = 0; n < 4; ++n) bf[n] = *(const bf16x8*)&Bs[cur * 4096 + (wc + n * 16 + lr) * 32 + swz8];
    #pragma unroll
    for (int m = 0; m < 4; ++m)
      #pragma unroll
      for (int n = 0; n < 4; ++n)
        acc[m][n] = __builtin_amdgcn_mfma_f32_16x16x32_bf16(af[m], bf[n], acc[m][n], 0, 0, 0);
    __syncthreads();
  }

  const int lq4 = (lane >> 4) * 4;
  #pragma unroll
  for (int m = 0; m < 4; ++m)
    #pragma unroll
    for (int r = 0; r < 4; ++r) {
      size_t row = (size_t)(m0 + wr + m * 16 + lq4 + r) * CC;
      #pragma unroll
      for (int n = 0; n < 4; ++n) {
        int o = o0 + wc + n * 16 + lr;
        Y[row + o] = f2b(acc[m][n][r] + bias[o]);
      }
    }
}

// 3 independent GEMMs (q,k,v) in one launch
__global__ __launch_bounds__(256) void gemm_tc3(
    const short* __restrict__ A0, const short* __restrict__ A1, const short* __restrict__ A2,
    const short* __restrict__ W0, const short* __restrict__ W1, const short* __restrict__ W2,
    const float* __restrict__ b0, const float* __restrict__ b1, const float* __restrict__ b2,
    short* __restrict__ Y0, short* __restrict__ Y1, short* __restrict__ Y2)
{
  __shared__ short As[2 * 4096];
  __shared__ short Bs[2 * 4096];
  const short *A, *W; const float* bias; short* Y;
  switch (blockIdx.y) {
    case 0:  A = A0; W = W0; bias = b0; Y = Y0; break;
    case 1:  A = A1; W = W1; bias = b1; Y = Y1; break;
    default: A = A2; W = W2; bias = b2; Y = Y2; break;
  }
  gemm_body(A, W, bias, Y, As, Bs, blockIdx.x, threadIdx.x);
}

// ---------------------------------------------------------------------------
// Row feature kernel on [row][512] bf16, wave per row, in-place; all 3
// tensors in one launch (blockIdx.y = mode).
// mode 0=Q (rms->elu+1->per-head softmax->*8^-0.5)
//      1=K (rms->elu+1->EXP, masked rows -> 0)   [normalization deferred]
//      2=V (rms->elu+1->/64)
// ---------------------------------------------------------------------------
__global__ __launch_bounds__(256) void feat_all(short* __restrict__ qf, short* __restrict__ kf,
                                                short* __restrict__ vf,
                                                const float* __restrict__ gq,
                                                const float* __restrict__ gk,
                                                const float* __restrict__ gv,
                                                const unsigned char* __restrict__ mask)
{
  const int mode = blockIdx.y;
  short* buf = mode == 0 ? qf : (mode == 1 ? kf : vf);
  const float* g = mode == 0 ? gq : (mode == 1 ? gk : gv);
  const int row = blockIdx.x * 4 + (threadIdx.x >> 6);
  const int lane = threadIdx.x & 63;
  short* p = buf + (size_t)row * CC + lane * 8;
  if (mode == 1 && mask[row]) {            // whole (b,t) row masked -> exp = 0
    bf16x8 z = { 0,0,0,0,0,0,0,0 };
    *(bf16x8*)p = z;
    return;
  }
  bf16x8 v = *(const bf16x8*)p;
  float x[8], ss = 0.f;
  #pragma unroll
  for (int j = 0; j < 8; ++j) { x[j] = b2f(v[j]); ss += x[j] * x[j]; }
  #pragma unroll
  for (int off = 32; off; off >>= 1) ss += __shfl_xor(ss, off);
  float rn = rsqrtf(ss * (1.0f / CC) + EPS);
  float4 g0 = *(const float4*)(g + lane * 8);
  float4 g1 = *(const float4*)(g + lane * 8 + 4);
  float gv8[8] = { g0.x, g0.y, g0.z, g0.w, g1.x, g1.y, g1.z, g1.w };
  float f[8];
  #pragma unroll
  for (int j = 0; j < 8; ++j) {
    float t = x[j] * rn * gv8[j];
    f[j] = t > 0.f ? t + 1.f : __expf(t);
  }
  bf16x8 o;
  if (mode == 1) {
    #pragma unroll
    for (int j = 0; j < 8; ++j) o[j] = f2b(__expf(f[j]));   // unnormalized exp
  } else if (mode == 2) {
    #pragma unroll
    for (int j = 0; j < 8; ++j) o[j] = f2b(f[j] * (1.0f / DH));
  } else {  // Q: softmax over head (64 c = 8 lanes), no max-sub (f <= ~24)
    float ls = 0.f;
    #pragma unroll
    for (int j = 0; j < 8; ++j) { f[j] = __expf(f[j]); ls += f[j]; }
    ls += __shfl_xor(ls, 1); ls += __shfl_xor(ls, 2); ls += __shfl_xor(ls, 4);
    float sc = 0.35355339059327373f / ls;     // 8^-0.5 / sum
    #pragma unroll
    for (int j = 0; j < 8; ++j) o[j] = f2b(f[j] * sc);
  }
  *(bf16x8*)p = o;
}

// column-sum of kf_exp over t: S[b][c] = sum_t kfe[b][t][c]
__global__ __launch_bounds__(256) void ksm_sum(const short* __restrict__ kfe,
                                               float* __restrict__ S)
{
  const int b = blockIdx.y, tch = blockIdx.x;
  const int c2 = threadIdx.x * 2;
  float s0 = 0.f, s1 = 0.f;
  for (int t = 0; t < 128; ++t) {
    unsigned u = *(const unsigned*)&kfe[((size_t)b * TT + tch * 128 + t) * CC + c2];
    s0 += __uint_as_float(u << 16);
    s1 += __uint_as_float(u & 0xffff0000u);
  }
  atomicAdd(&S[b * CC + c2], s0);
  atomicAdd(&S[b * CC + c2 + 1], s1);
}

// ---------------------------------------------------------------------------
// ctx partials from t-major kfe/vf: P[tc][bh][q][v] = sum_t kfe[t][q]*vf[t][v]
// ---------------------------------------------------------------------------
__global__ __launch_bounds__(256) void ctx_t(const short* __restrict__ kf,
                                             const short* __restrict__ vf,
                                             float* __restrict__ P)
{
  __shared__ short Ks[64 * 64];
  __shared__ short Vs[64 * 64];
  const int tc = blockIdx.x, bh = blockIdx.y;
  const int b = bh >> 3, h = bh & 7;
  const int tid = threadIdx.x, wid = tid >> 6, lane = tid & 63;
  const int lr = lane & 15, lg = lane >> 4;
  f32x4 acc[4] = {};

  for (int ts = 0; ts < 8; ++ts) {
    #pragma unroll
    for (int i = 0; i < 2; ++i) {
      int n = i * 256 + tid;
      int t = n >> 3, ch = (n & 7) * 8;
      size_t src = ((size_t)b * TT + tc * 512 + ts * 64 + t) * CC + h * DH + ch;
      gld16(Ks + n * 8, kf + src);
      gld16(Vs + n * 8, vf + src);
    }
    __syncthreads();
    #pragma unroll
    for (int kk = 0; kk < 64; kk += 32) {
      short a[8];
      #pragma unroll
      for (int j = 0; j < 8; ++j)
        a[j] = Ks[(kk + lg * 8 + j) * 64 + wid * 16 + lr];
      bf16x8 af = *(const bf16x8*)&a[0];
      #pragma unroll
      for (int n = 0; n < 4; ++n) {
        short bv[8];
        #pragma unroll
        for (int j = 0; j < 8; ++j)
          bv[j] = Vs[(kk + lg * 8 + j) * 64 + n * 16 + lr];
        acc[n] = __builtin_amdgcn_mfma_f32_16x16x32_bf16(af, *(const bf16x8*)&bv[0],
                                                         acc[n], 0, 0, 0);
      }
    }
    __syncthreads();
  }
  float* pp = P + ((size_t)tc * 64 + bh) * (DH * DH);
  const int lq4 = lg * 4;
  #pragma unroll
  for (int n = 0; n < 4; ++n)
    #pragma unroll
    for (int r = 0; r < 4; ++r)
      pp[(wid * 16 + lq4 + r) * DH + n * 16 + lr] = acc[n][r];
}

// reduce chunk partials, apply 1/S (deferred k-softmax norm), emit CT[bh][v][q]
__global__ __launch_bounds__(256) void ctx_reduce(const float* __restrict__ P,
                                                  const float* __restrict__ S,
                                                  short* __restrict__ CT)
{
  int i = blockIdx.x * 256 + threadIdx.x;    // (bh, q, v), v fastest
  float s = 0.f;
  #pragma unroll
  for (int c = 0; c < 8; ++c) s += P[(size_t)c * 64 * DH * DH + i];
  int bh = i >> 12, rem = i & 4095, q = rem >> 6, v = rem & 63;
  int b = bh >> 3, h = bh & 7;
  float inv = 1.f / S[b * CC + h * DH + q];
  CT[((size_t)bh << 12) + v * 64 + q] = f2b(s * inv);
}

// ---------------------------------------------------------------------------
// FUSED attn + proj: pj[row][o] = sum_h sum_v ao_h[row][v] * Wp[o][h*64+v]
// where ao_h[row][v] = sum_q qf[row][h*64+q] * CT[bh][v][q].
// Block = 128 rows x 128 outs, 4 waves, loop h=0..7:
//   stage qf-chunk/CT/Wp-chunk -> MFMA ao-chunk -> LDS (bf16) -> MFMA vs Wp.
// ao never touches HBM (saves 64 MB roundtrip + a launch); qf re-read x4
// o-tiles is L2-resident (same-XCD swizzle).
// ---------------------------------------------------------------------------
__global__ __launch_bounds__(256) void attn_proj(const short* __restrict__ qf,
                                                 const short* __restrict__ CT,
                                                 const short* __restrict__ Wp,
                                                 const float* __restrict__ bp,
                                                 short* __restrict__ pj)
{
  __shared__ short Qs[128 * 72];    // qf chunk [row][64q]
  __shared__ short Cs[64 * 72];     // CT[bh]   [v][64q]
  __shared__ short Ws2[128 * 72];   // Wp chunk [o][64c]
  __shared__ short AOs[128 * 72];   // ao chunk [row][64v] bf16
  const int tid = threadIdx.x;
  int x = blockIdx.x;
  int wg = (x & 7) * 128 + (x >> 3);       // XCD-chunked
  const int m0 = (wg >> 2) * 128;
  const int o0 = (wg & 3) * 128;
  const int wid = tid >> 6, lane = tid & 63;
  const int lr = lane & 15, lg = lane >> 4, lk8 = lg * 8;
  const int wr = (wid >> 1) * 64, wc = (wid & 1) * 64;
  const int bh0 = (m0 >> 12) * 8;          // blocks never straddle a batch

  f32x4 acc[4][4] = {};

  for (int h = 0; h < 8; ++h) {
    // stage qf chunk + Wp chunk (1024 x 16B each) and CT (512 x 16B)
    #pragma unroll
    for (int i = 0; i < 4; ++i) {
      int n = i * 256 + tid;
      int r = n >> 3, ch = (n & 7) * 8;
      *(bf16x8*)&Qs[r * 72 + ch]  = *(const bf16x8*)(qf + (size_t)(m0 + r) * CC + h * DH + ch);
      *(bf16x8*)&Ws2[r * 72 + ch] = *(const bf16x8*)(Wp + (size_t)(o0 + r) * CC + h * DH + ch);
    }
    #pragma unroll
    for (int i = 0; i < 2; ++i) {
      int n = i * 256 + tid;
      int v = n >> 3, ch = (n & 7) * 8;
      *(bf16x8*)&Cs[v * 72 + ch] = *(const bf16x8*)(CT + ((size_t)(bh0 + h) << 12) + v * 64 + ch);
    }
    __syncthreads();

    // ao chunk: wave computes rows [wid*32, +32) x 64 v
    f32x4 aoacc[2][4] = {};
    #pragma unroll
    for (int ks = 0; ks < 2; ++ks) {
      bf16x8 afq[2], cfv[4];
      #pragma unroll
      for (int mf = 0; mf < 2; ++mf)
        afq[mf] = *(const bf16x8*)&Qs[(wid * 32 + mf * 16 + lr) * 72 + ks * 32 + lk8];
      #pragma unroll
      for (int nf = 0; nf < 4; ++nf)
        cfv[nf] = *(const bf16x8*)&Cs[(nf * 16 + lr) * 72 + ks * 32 + lk8];
      #pragma unroll
      for (int mf = 0; mf < 2; ++mf)
        #pragma unroll
        for (int nf = 0; nf < 4; ++nf)
          aoacc[mf][nf] = __builtin_amdgcn_mfma_f32_16x16x32_bf16(afq[mf], cfv[nf], aoacc[mf][nf], 0, 0, 0);
    }
    // write ao chunk (bf16) to LDS: D row=(lane>>4)*4+r, col=lane&15
    #pragma unroll
    for (int mf = 0; mf < 2; ++mf)
      #pragma unroll
      for (int r = 0; r < 4; ++r) {
        int row = wid * 32 + mf * 16 + lg * 4 + r;
        #pragma unroll
        for (int nf = 0; nf < 4; ++nf)
          AOs[row * 72 + nf * 16 + lr] = f2b(aoacc[mf][nf][r]);
      }
    __syncthreads();

    // proj MFMA: quadrant (wr, wc), K = 64 (this h's v-chunk)
    #pragma unroll
    for (int ks = 0; ks < 2; ++ks) {
      bf16x8 afa[4], bfw[4];
      #pragma unroll
      for (int mf = 0; mf < 4; ++mf)
        afa[mf] = *(const bf16x8*)&AOs[(wr + mf * 16 + lr) * 72 + ks * 32 + lk8];
      #pragma unroll
      for (int nf = 0; nf < 4; ++nf)
        bfw[nf] = *(const bf16x8*)&Ws2[(wc + nf * 16 + lr) * 72 + ks * 32 + lk8];
      #pragma unroll
      for (int mf = 0; mf < 4; ++mf)
        #pragma unroll
        for (int nf = 0; nf < 4; ++nf)
          acc[mf][nf] = __builtin_amdgcn_mfma_f32_16x16x32_bf16(afa[mf], bfw[nf], acc[mf][nf], 0, 0, 0);
    }
    __syncthreads();   // before next h overwrites Qs/Cs/Ws2/AOs
  }

  const int lq4 = lg * 4;
  #pragma unroll
  for (int mf = 0; mf < 4; ++mf)
    #pragma unroll
    for (int r = 0; r < 4; ++r) {
      size_t row = (size_t)(m0 + wr + mf * 16 + lq4 + r) * CC;
      #pragma unroll
      for (int nf = 0; nf < 4; ++nf) {
        int o = o0 + wc + nf * 16 + lr;
        pj[row + o] = f2b(acc[mf][nf][r] + bp[o]);
      }
    }
}

// ---------------------------------------------------------------------------
// fused final: single global read. Pass1 computes rms AND stores z=pj+qt
// as bf16 into LDS z[c][t] (stride 72). Pass2 reads z rows (b128), scales by
// rms[t]*g[c], coalesced float4 stores to [c][t].
// ---------------------------------------------------------------------------
__global__ __launch_bounds__(256) void final_fused(const short* __restrict__ pj,
                                                   const short* __restrict__ qt,
                                                   const float* __restrict__ g,
                                                   float* __restrict__ out)
{
  __shared__ short z[512 * 72];            // 72 KB
  __shared__ float rmss[64];
  const int t0 = blockIdx.x * 64, b = blockIdx.y;
  const int tid = threadIdx.x;

  {
    const int t = tid >> 2, cb = (tid & 3) * 128;
    const size_t row = ((size_t)b * TT + t0 + t) * CC + cb;
    float ss = 0.f;
    #pragma unroll
    for (int j = 0; j < 16; ++j) {
      bf16x8 a = *(const bf16x8*)(pj + row + j * 8);
      bf16x8 q = *(const bf16x8*)(qt + row + j * 8);
      #pragma unroll
      for (int e = 0; e < 8; ++e) {
        float zf = b2f(a[e]) + b2f(q[e]);
        ss += zf * zf;
        z[(cb + j * 8 + e) * 72 + t] = f2b(zf);
      }
    }
    ss += __shfl_xor(ss, 1);
    ss += __shfl_xor(ss, 2);
    if ((tid & 3) == 0) rmss[t] = rsqrtf(ss * (1.0f / CC) + EPS);
  }
  __syncthreads();

  const int c = tid >> 2, tcs = (tid & 3) * 16;
  #pragma unroll 1
  for (int cb8 = 0; cb8 < 8; ++cb8) {
    const int cc = cb8 * 64 + c;
    const float gc = g[cc];
    bf16x8 z0 = *(const bf16x8*)&z[cc * 72 + tcs];
    bf16x8 z1 = *(const bf16x8*)&z[cc * 72 + tcs + 8];
    float* dst = out + ((size_t)b * CC + cc) * TT + t0 + tcs;
    #pragma unroll
    for (int i = 0; i < 2; ++i) {
      float4 o0 = { b2f(z0[i*4+0]) * rmss[tcs+i*4+0] * gc, b2f(z0[i*4+1]) * rmss[tcs+i*4+1] * gc,
                    b2f(z0[i*4+2]) * rmss[tcs+i*4+2] * gc, b2f(z0[i*4+3]) * rmss[tcs+i*4+3] * gc };
      *(float4*)(dst + i * 4) = o0;
    }
    #pragma unroll
    for (int i = 0; i < 2; ++i) {
      float4 o1 = { b2f(z1[i*4+0]) * rmss[tcs+8+i*4+0] * gc, b2f(z1[i*4+1]) * rmss[tcs+8+i*4+1] * gc,
                    b2f(z1[i*4+2]) * rmss[tcs+8+i*4+2] * gc, b2f(z1[i*4+3]) * rmss[tcs+8+i*4+3] * gc };
      *(float4*)(dst + 8 + i * 4) = o1;
    }
  }
}

// ---------------------------------------------------------------------------
extern "C" void kernel_launch(void* const* d_in, const int* in_sizes, int n_in,
                              void* d_out, int out_size, void* d_ws, size_t ws_size,
                              hipStream_t stream) {
  (void)in_sizes; (void)n_in; (void)out_size; (void)ws_size;
  const float* queries = (const float*)d_in[0];
  const float* keys    = (const float*)d_in[1];
  const float* values  = (const float*)d_in[2];
  const unsigned char* mask = (const unsigned char*)d_in[3];
  const float* Wq = (const float*)d_in[4];
  const float* bq = (const float*)d_in[5];
  const float* gq = (const float*)d_in[6];
  const float* Wk = (const float*)d_in[7];
  const float* bk = (const float*)d_in[8];
  const float* gk = (const float*)d_in[9];
  const float* Wv = (const float*)d_in[10];
  const float* bv = (const float*)d_in[11];
  const float* gv = (const float*)d_in[12];
  const float* Wp = (const float*)d_in[13];
  const float* bp = (const float*)d_in[14];
  const float* g_out = (const float*)d_in[15];

  const size_t NCT = (size_t)NROWS * CC;       // 16,777,216 elements
  short* qt = (short*)d_ws;                    // bf16 [row][c] transposed inputs
  short* kt = qt + NCT;
  short* vt = kt + NCT;
  short* qf = vt + NCT;                        // feature outputs
  short* kf = qf + NCT;
  short* vf = kf + NCT;
  short* pj = vt;                              // reuse (vt dead after gemm_tc3)
  float* ctxP = (float*)(vf + NCT);            // 8 x 64 x 4096 fp32
  short* CT  = (short*)(ctxP + (size_t)8 * 64 * DH * DH);   // [bh][v][q] bf16
  short* wqb = CT + (size_t)64 * DH * DH;
  short* wkb = wqb + (size_t)CC * CC;
  short* wvb = wkb + (size_t)CC * CC;
  short* wpb = wvb + (size_t)CC * CC;
  float* S   = (float*)(wpb + (size_t)CC * CC);   // [B][C] softmax sums

  hipMemsetAsync(S, 0, (size_t)BB * CC * sizeof(float), stream);

  conv_w4<<<dim3(CC * CC / 2048, 4), 256, 0, stream>>>(Wq, Wk, Wv, Wp, wqb, wkb, wvb, wpb);

  transpose_cvt3<<<dim3(TT / 256, CC / 64, 3 * BB), 256, 0, stream>>>(
      queries, keys, values, qt, kt, vt);

  gemm_tc3<<<dim3(1024, 3), 256, 0, stream>>>(qt, kt, vt, wqb, wkb, wvb,
                                              bq, bk, bv, qf, kf, vf);

  feat_all<<<dim3(NROWS / 4, 3), 256, 0, stream>>>(qf, kf, vf, gq, gk, gv, mask);

  ksm_sum<<<dim3(32, BB), 256, 0, stream>>>(kf, S);

  ctx_t<<<dim3(8, BB * HH), 256, 0, stream>>>(kf, vf, ctxP);
  ctx_reduce<<<dim3(64 * DH * DH / 256), 256, 0, stream>>>(ctxP, S, CT);

  attn_proj<<<dim3(1024), 256, 0, stream>>>(qf, CT, wpb, bp, pj);

  final_fused<<<dim3(TT / 64, BB), 256, 0, stream>>>(pj, qt, g_out, (float*)d_out);
}

// Round 15
// 298.541 us; speedup vs baseline: 1.1207x; 1.0833x over previous
//
#include <hip/hip_runtime.h>
#include <hip/hip_bf16.h>

// Problem constants (fixed by the reference)
#define BB 8
#define CC 512
#define TT 4096
#define HH 8
#define DH 64
#define EPS 1e-6f

#define NROWS (BB * TT)          // 32768 flat (b,t) rows

using bf16x8 = __attribute__((ext_vector_type(8))) short;
using s16x4  = __attribute__((ext_vector_type(4))) short;
using f32x4  = __attribute__((ext_vector_type(4))) float;

__device__ __forceinline__ short f2b(float f) {
  __hip_bfloat16 h = __float2bfloat16(f);
  return *reinterpret_cast<short*>(&h);
}
__device__ __forceinline__ float b2f(short s) {
  unsigned u = ((unsigned)(unsigned short)s) << 16;
  return __uint_as_float(u);
}

// async global->LDS 16B copy (dest must be wave-uniform base + lane*16)
__device__ __forceinline__ void gld16(short* lds_dst, const short* gsrc) {
  __builtin_amdgcn_global_load_lds(
      (const __attribute__((address_space(1))) unsigned int*)gsrc,
      (__attribute__((address_space(3))) unsigned int*)lds_dst, 16, 0, 0);
}

// 4 weights fp32 [o][c] -> bf16 [o][c], one launch
__global__ __launch_bounds__(256) void conv_w4(const float* __restrict__ s0, const float* __restrict__ s1,
                                               const float* __restrict__ s2, const float* __restrict__ s3,
                                               short* __restrict__ d0, short* __restrict__ d1,
                                               short* __restrict__ d2, short* __restrict__ d3)
{
  const float* src; short* dst;
  switch (blockIdx.y) {
    case 0: src = s0; dst = d0; break;
    case 1: src = s1; dst = d1; break;
    case 2: src = s2; dst = d2; break;
    default: src = s3; dst = d3; break;
  }
  int i8 = (blockIdx.x * 256 + threadIdx.x) * 8;
  float4 a = *(const float4*)(src + i8);
  float4 b = *(const float4*)(src + i8 + 4);
  bf16x8 h = { f2b(a.x), f2b(a.y), f2b(a.z), f2b(a.w),
               f2b(b.x), f2b(b.y), f2b(b.z), f2b(b.w) };
  *(bf16x8*)(dst + i8) = h;
}

// ---------------------------------------------------------------------------
// transpose+convert (r10 best-measured), QUERIES ONLY: fp32 [b][c][t] ->
// bf16 [b][t][c]. grid (T/256, C/64, B).
// ---------------------------------------------------------------------------
#define TSTR 120
__device__ __forceinline__ int tadr(int c, int t) {
  return c * TSTR + ((c >> 3) & 7) * 8 + t;
}

__global__ __launch_bounds__(256) void transpose_cvt1(const float* __restrict__ X,
                                                      short* __restrict__ Xt)
{
  __shared__ short tile[2][64 * TSTR];
  const int t0 = blockIdx.x * 256, c0 = blockIdx.y * 64, b = blockIdx.z;
  const int tid = threadIdx.x;
  const int cl = tid >> 4, t4 = (tid & 15) * 4;       // phase A coords
  const int T2 = (tid >> 3) * 2, ci = (tid & 7) * 8;  // phase B coords

  float4 r[4];
  #pragma unroll
  for (int it = 0; it < 4; ++it)
    r[it] = *(const float4*)(X + ((size_t)b * CC + c0 + it * 16 + cl) * TT + t0 + t4);

  for (int s = 0; s < 4; ++s) {
    const int cur = s & 1;
    #pragma unroll
    for (int it = 0; it < 4; ++it) {
      s16x4 h = { f2b(r[it].x), f2b(r[it].y), f2b(r[it].z), f2b(r[it].w) };
      *(s16x4*)&tile[cur][tadr(it * 16 + cl, t4)] = h;
    }
    if (s < 3) {
      #pragma unroll
      for (int it = 0; it < 4; ++it)
        r[it] = *(const float4*)(X + ((size_t)b * CC + c0 + it * 16 + cl) * TT
                                 + t0 + (s + 1) * 64 + t4);
    }
    __syncthreads();
    unsigned u[8];
    #pragma unroll
    for (int i = 0; i < 8; ++i)
      u[i] = *(const unsigned*)&tile[cur][tadr(ci + i, T2)];
    short lo[8], hi[8];
    #pragma unroll
    for (int i = 0; i < 8; ++i) {
      lo[i] = (short)(u[i] & 0xffffu);
      hi[i] = (short)(u[i] >> 16);
    }
    short* dst0 = Xt + ((size_t)b * TT + t0 + s * 64 + T2) * CC + c0 + ci;
    *(bf16x8*)dst0 = *(bf16x8*)&lo[0];
    *(bf16x8*)(dst0 + CC) = *(bf16x8*)&hi[0];
  }
}

// ---------------------------------------------------------------------------
// GEMM from bf16 A (r10 measured-best): Y[m][o] = sum_c A[m][c]*W[o][c]+bias.
// 128x128, BK=32, double-buffered LDS, both-sides XOR swizzle, gld16 staging.
// ---------------------------------------------------------------------------
__global__ __launch_bounds__(256) void gemm_tc(const short* __restrict__ A,
                                               const short* __restrict__ W,
                                               const float* __restrict__ bias,
                                               short* __restrict__ Y)
{
  __shared__ short As[2 * 4096];
  __shared__ short Bs[2 * 4096];
  const int tid = threadIdx.x;
  int x = blockIdx.x;
  int wg = (x & 7) * 128 + (x >> 3);       // XCD-chunked
  const int m0 = (wg >> 2) * 128;
  const int o0 = (wg & 3) * 128;

  const int wid = tid >> 6, lane = tid & 63;
  const int wr = (wid >> 1) * 64, wc = (wid & 1) * 64;
  const int lr = lane & 15, g = lane >> 4;
  const int swz8 = (g ^ ((lr >> 1) & 3)) * 8;
  const int srow0 = tid >> 2;
  const int scol  = ((tid & 3) ^ ((tid >> 3) & 3)) * 8;

  f32x4 acc[4][4] = {};

  #pragma unroll
  for (int it = 0; it < 2; ++it) {
    int row = it * 64 + srow0;
    gld16(&As[it * 2048 + tid * 8], A + (size_t)(m0 + row) * CC + scol);
    gld16(&Bs[it * 2048 + tid * 8], W + (size_t)(o0 + row) * CC + scol);
  }
  __syncthreads();

  for (int step = 0; step < 16; ++step) {
    const int cur = step & 1;
    if (step < 15) {
      const int k0 = (step + 1) * 32;
      #pragma unroll
      for (int it = 0; it < 2; ++it) {
        int row = it * 64 + srow0;
        gld16(&As[(cur ^ 1) * 4096 + it * 2048 + tid * 8], A + (size_t)(m0 + row) * CC + k0 + scol);
        gld16(&Bs[(cur ^ 1) * 4096 + it * 2048 + tid * 8], W + (size_t)(o0 + row) * CC + k0 + scol);
      }
    }
    bf16x8 af[4], bf[4];
    #pragma unroll
    for (int m = 0; m < 4; ++m) af[m] = *(const bf16x8*)&As[cur * 4096 + (wr + m * 16 + lr) * 32 + swz8];
    #pragma unroll
    for (int n = 0; n < 4; ++n) bf[n] = *(const bf16x8*)&Bs[cur * 4096 + (wc + n * 16 + lr) * 32 + swz8];
    #pragma unroll
    for (int m = 0; m < 4; ++m)
      #pragma unroll
      for (int n = 0; n < 4; ++n)
        acc[m][n] = __builtin_amdgcn_mfma_f32_16x16x32_bf16(af[m], bf[n], acc[m][n], 0, 0, 0);
    __syncthreads();
  }

  const int lq4 = (lane >> 4) * 4;
  #pragma unroll
  for (int m = 0; m < 4; ++m)
    #pragma unroll
    for (int r = 0; r < 4; ++r) {
      size_t row = (size_t)(m0 + wr + m * 16 + lq4 + r) * CC;
      #pragma unroll
      for (int n = 0; n < 4; ++n) {
        int o = o0 + wc + n * 16 + lr;
        Y[row + o] = f2b(acc[m][n][r] + bias[o]);
      }
    }
}

// ---------------------------------------------------------------------------
// GEMM from fp32 A DIRECTLY (kills the k/v transpose): A = X[b][c][t] fp32.
// Per K-step: thread reads 4x float4 rows (coalesced 512 B/wave), converts,
// writes transposed s16x4 into Am[m=t][k=c] (stride 40 + pad((m>>2)&7)*8:
// writes ~4-way min, b128 frag reads ~2-4-way). W path identical to gemm_tc.
// grid (1024, 2): y=0 keys->kf, y=1 values->vf.
// ---------------------------------------------------------------------------
#define AST 40
__device__ __forceinline__ int aadr(int m, int c) {
  return m * AST + ((m >> 2) & 7) * 8 + c;
}

__global__ __launch_bounds__(256) void gemm_direct2(
    const float* __restrict__ X0, const float* __restrict__ X1,
    const short* __restrict__ W0, const short* __restrict__ W1,
    const float* __restrict__ b0, const float* __restrict__ b1,
    short* __restrict__ Y0, short* __restrict__ Y1)
{
  __shared__ short Am[2][5184];
  __shared__ short Ws[2][4096];
  const float* Xf = blockIdx.y == 0 ? X0 : X1;
  const short* W  = blockIdx.y == 0 ? W0 : W1;
  const float* bias = blockIdx.y == 0 ? b0 : b1;
  short* Y        = blockIdx.y == 0 ? Y0 : Y1;

  const int tid = threadIdx.x;
  int x = blockIdx.x;
  int wg = (x & 7) * 128 + (x >> 3);       // XCD-chunked
  const int m0 = (wg >> 2) * 128;
  const int o0 = (wg & 3) * 128;
  const int b = m0 >> 12, t0 = m0 & 4095;  // 128-row tiles never straddle b
  const float* Xb = Xf + (size_t)b * CC * TT + t0;

  const int wid = tid >> 6, lane = tid & 63;
  const int wr = (wid >> 1) * 64, wc = (wid & 1) * 64;
  const int lr = lane & 15, g = lane >> 4;
  const int lk8 = g * 8;
  const int swz8 = (g ^ ((lr >> 1) & 3)) * 8;            // W read swizzle
  const int srow0 = tid >> 2;
  const int scol  = ((tid & 3) ^ ((tid >> 3) & 3)) * 8;  // W source swizzle

  const int t4 = (tid & 31) * 4;           // A staging coords
  const int c4 = (tid >> 5) * 4;

  f32x4 acc[4][4] = {};

  // prologue: step-0 A register loads + W gld16
  float4 rc[4];
  #pragma unroll
  for (int j = 0; j < 4; ++j)
    rc[j] = *(const float4*)(Xb + (size_t)(c4 + j) * TT + t4);
  #pragma unroll
  for (int it = 0; it < 2; ++it)
    gld16(&Ws[0][it * 2048 + tid * 8], W + (size_t)(o0 + it * 64 + srow0) * CC + scol);

  for (int step = 0; step < 16; ++step) {
    const int cur = step & 1;
    // issue next-step loads first (overlap with convert below)
    float4 rn[4];
    if (step < 15) {
      const int k0 = (step + 1) * 32;
      #pragma unroll
      for (int j = 0; j < 4; ++j)
        rn[j] = *(const float4*)(Xb + (size_t)(k0 + c4 + j) * TT + t4);
      #pragma unroll
      for (int it = 0; it < 2; ++it)
        gld16(&Ws[cur ^ 1][it * 2048 + tid * 8], W + (size_t)(o0 + it * 64 + srow0) * CC + k0 + scol);
    }
    // convert current regs, write transposed into Am[cur]
    #pragma unroll
    for (int jt = 0; jt < 4; ++jt) {
      int m = t4 + jt;
      s16x4 h = { f2b(rc[0][jt]), f2b(rc[1][jt]), f2b(rc[2][jt]), f2b(rc[3][jt]) };
      *(s16x4*)&Am[cur][aadr(m, c4)] = h;
    }
    __syncthreads();

    bf16x8 af[4], bf[4];
    #pragma unroll
    for (int m = 0; m < 4; ++m) af[m] = *(const bf16x8*)&Am[cur][aadr(wr + m * 16 + lr, lk8)];
    #pragma unroll
    for (int n = 0; n < 4; ++n) bf[n] = *(const bf16x8*)&Ws[cur][(wc + n * 16 + lr) * 32 + swz8];
    #pragma unroll
    for (int m = 0; m < 4; ++m)
      #pragma unroll
      for (int n = 0; n < 4; ++n)
        acc[m][n] = __builtin_amdgcn_mfma_f32_16x16x32_bf16(af[m], bf[n], acc[m][n], 0, 0, 0);
    __syncthreads();

    #pragma unroll
    for (int j = 0; j < 4; ++j) rc[j] = rn[j];
  }

  const int lq4 = (lane >> 4) * 4;
  #pragma unroll
  for (int m = 0; m < 4; ++m)
    #pragma unroll
    for (int r = 0; r < 4; ++r) {
      size_t row = (size_t)(m0 + wr + m * 16 + lq4 + r) * CC;
      #pragma unroll
      for (int n = 0; n < 4; ++n) {
        int o = o0 + wc + n * 16 + lr;
        Y[row + o] = f2b(acc[m][n][r] + bias[o]);
      }
    }
}

// ---------------------------------------------------------------------------
// Row feature kernel on [row][512] bf16, wave per row, in-place; all 3
// tensors in one launch (blockIdx.y = mode).
// mode 0=Q (rms->elu+1->per-head softmax->*8^-0.5)
//      1=K (rms->elu+1->EXP, masked rows -> 0)   [normalization deferred]
//      2=V (rms->elu+1->/64)
// ---------------------------------------------------------------------------
__global__ __launch_bounds__(256) void feat_all(short* __restrict__ qf, short* __restrict__ kf,
                                                short* __restrict__ vf,
                                                const float* __restrict__ gq,
                                                const float* __restrict__ gk,
                                                const float* __restrict__ gv,
                                                const unsigned char* __restrict__ mask)
{
  const int mode = blockIdx.y;
  short* buf = mode == 0 ? qf : (mode == 1 ? kf : vf);
  const float* g = mode == 0 ? gq : (mode == 1 ? gk : gv);
  const int row = blockIdx.x * 4 + (threadIdx.x >> 6);
  const int lane = threadIdx.x & 63;
  short* p = buf + (size_t)row * CC + lane * 8;
  if (mode == 1 && mask[row]) {            // whole (b,t) row masked -> exp = 0
    bf16x8 z = { 0,0,0,0,0,0,0,0 };
    *(bf16x8*)p = z;
    return;
  }
  bf16x8 v = *(const bf16x8*)p;
  float x[8], ss = 0.f;
  #pragma unroll
  for (int j = 0; j < 8; ++j) { x[j] = b2f(v[j]); ss += x[j] * x[j]; }
  #pragma unroll
  for (int off = 32; off; off >>= 1) ss += __shfl_xor(ss, off);
  float rn = rsqrtf(ss * (1.0f / CC) + EPS);
  float4 g0 = *(const float4*)(g + lane * 8);
  float4 g1 = *(const float4*)(g + lane * 8 + 4);
  float gv8[8] = { g0.x, g0.y, g0.z, g0.w, g1.x, g1.y, g1.z, g1.w };
  float f[8];
  #pragma unroll
  for (int j = 0; j < 8; ++j) {
    float t = x[j] * rn * gv8[j];
    f[j] = t > 0.f ? t + 1.f : __expf(t);
  }
  bf16x8 o;
  if (mode == 1) {
    #pragma unroll
    for (int j = 0; j < 8; ++j) o[j] = f2b(__expf(f[j]));   // unnormalized exp
  } else if (mode == 2) {
    #pragma unroll
    for (int j = 0; j < 8; ++j) o[j] = f2b(f[j] * (1.0f / DH));
  } else {  // Q: softmax over head (64 c = 8 lanes), no max-sub (f <= ~24)
    float ls = 0.f;
    #pragma unroll
    for (int j = 0; j < 8; ++j) { f[j] = __expf(f[j]); ls += f[j]; }
    ls += __shfl_xor(ls, 1); ls += __shfl_xor(ls, 2); ls += __shfl_xor(ls, 4);
    float sc = 0.35355339059327373f / ls;     // 8^-0.5 / sum
    #pragma unroll
    for (int j = 0; j < 8; ++j) o[j] = f2b(f[j] * sc);
  }
  *(bf16x8*)p = o;
}

// column-sum of kf_exp over t: S[b][c] = sum_t kfe[b][t][c]
__global__ __launch_bounds__(256) void ksm_sum(const short* __restrict__ kfe,
                                               float* __restrict__ S)
{
  const int b = blockIdx.y, tch = blockIdx.x;
  const int c2 = threadIdx.x * 2;
  float s0 = 0.f, s1 = 0.f;
  for (int t = 0; t < 128; ++t) {
    unsigned u = *(const unsigned*)&kfe[((size_t)b * TT + tch * 128 + t) * CC + c2];
    s0 += __uint_as_float(u << 16);
    s1 += __uint_as_float(u & 0xffff0000u);
  }
  atomicAdd(&S[b * CC + c2], s0);
  atomicAdd(&S[b * CC + c2 + 1], s1);
}

// ---------------------------------------------------------------------------
// ctx partials from t-major kfe/vf: P[tc][bh][q][v] = sum_t kfe[t][q]*vf[t][v]
// ---------------------------------------------------------------------------
__global__ __launch_bounds__(256) void ctx_t(const short* __restrict__ kf,
                                             const short* __restrict__ vf,
                                             float* __restrict__ P)
{
  __shared__ short Ks[64 * 64];
  __shared__ short Vs[64 * 64];
  const int tc = blockIdx.x, bh = blockIdx.y;
  const int b = bh >> 3, h = bh & 7;
  const int tid = threadIdx.x, wid = tid >> 6, lane = tid & 63;
  const int lr = lane & 15, lg = lane >> 4;
  f32x4 acc[4] = {};

  for (int ts = 0; ts < 8; ++ts) {
    #pragma unroll
    for (int i = 0; i < 2; ++i) {
      int n = i * 256 + tid;
      int t = n >> 3, ch = (n & 7) * 8;
      size_t src = ((size_t)b * TT + tc * 512 + ts * 64 + t) * CC + h * DH + ch;
      gld16(Ks + n * 8, kf + src);
      gld16(Vs + n * 8, vf + src);
    }
    __syncthreads();
    #pragma unroll
    for (int kk = 0; kk < 64; kk += 32) {
      short a[8];
      #pragma unroll
      for (int j = 0; j < 8; ++j)
        a[j] = Ks[(kk + lg * 8 + j) * 64 + wid * 16 + lr];
      bf16x8 af = *(const bf16x8*)&a[0];
      #pragma unroll
      for (int n = 0; n < 4; ++n) {
        short bv[8];
        #pragma unroll
        for (int j = 0; j < 8; ++j)
          bv[j] = Vs[(kk + lg * 8 + j) * 64 + n * 16 + lr];
        acc[n] = __builtin_amdgcn_mfma_f32_16x16x32_bf16(af, *(const bf16x8*)&bv[0],
                                                         acc[n], 0, 0, 0);
      }
    }
    __syncthreads();
  }
  float* pp = P + ((size_t)tc * 64 + bh) * (DH * DH);
  const int lq4 = lg * 4;
  #pragma unroll
  for (int n = 0; n < 4; ++n)
    #pragma unroll
    for (int r = 0; r < 4; ++r)
      pp[(wid * 16 + lq4 + r) * DH + n * 16 + lr] = acc[n][r];
}

// reduce chunk partials, apply 1/S (deferred k-softmax norm), emit CT[bh][v][q]
__global__ __launch_bounds__(256) void ctx_reduce(const float* __restrict__ P,
                                                  const float* __restrict__ S,
                                                  short* __restrict__ CT)
{
  int i = blockIdx.x * 256 + threadIdx.x;    // (bh, q, v), v fastest
  float s = 0.f;
  #pragma unroll
  for (int c = 0; c < 8; ++c) s += P[(size_t)c * 64 * DH * DH + i];
  int bh = i >> 12, rem = i & 4095, q = rem >> 6, v = rem & 63;
  int b = bh >> 3, h = bh & 7;
  float inv = 1.f / S[b * CC + h * DH + q];
  CT[((size_t)bh << 12) + v * 64 + q] = f2b(s * inv);
}

// ---------------------------------------------------------------------------
// attn: ao[row][h*64+v] = sum_q qf[row][h*64+q] * CT[bh][v][q]
// ---------------------------------------------------------------------------
__global__ __launch_bounds__(256) void attn_t(const short* __restrict__ qf,
                                              const short* __restrict__ CT,
                                              short* __restrict__ ao)
{
  __shared__ short As[128 * 72];
  __shared__ short Cs[64 * 72];
  const int m0 = blockIdx.x * 128, h = blockIdx.y;
  const int tid = threadIdx.x, wid = tid >> 6, lane = tid & 63;
  const int lr = lane & 15, lk8 = (lane >> 4) * 8;

  #pragma unroll
  for (int i = 0; i < 4; ++i) {
    int n = i * 256 + tid;
    int r = n >> 3, ch = (n & 7) * 8;
    *(bf16x8*)&As[r * 72 + ch] =
        *(const bf16x8*)(qf + (size_t)(m0 + r) * CC + h * DH + ch);
  }
  {
    const int bh0 = (m0 / TT) * 8 + h;
    #pragma unroll
    for (int i = 0; i < 2; ++i) {
      int n = i * 256 + tid;
      int v = n >> 3, ch = (n & 7) * 8;
      *(bf16x8*)&Cs[v * 72 + ch] = *(const bf16x8*)(CT + ((size_t)bh0 << 12) + v * 64 + ch);
    }
  }
  __syncthreads();

  const int wr = wid * 32;
  f32x4 acc[2][4] = {};
  #pragma unroll
  for (int kk = 0; kk < 64; kk += 32) {
    bf16x8 af[2], cf[4];
    #pragma unroll
    for (int m = 0; m < 2; ++m) af[m] = *(const bf16x8*)&As[(wr + m * 16 + lr) * 72 + kk + lk8];
    #pragma unroll
    for (int n = 0; n < 4; ++n) cf[n] = *(const bf16x8*)&Cs[(n * 16 + lr) * 72 + kk + lk8];
    #pragma unroll
    for (int m = 0; m < 2; ++m)
      #pragma unroll
      for (int n = 0; n < 4; ++n)
        acc[m][n] = __builtin_amdgcn_mfma_f32_16x16x32_bf16(af[m], cf[n], acc[m][n], 0, 0, 0);
  }
  const int lq4 = (lane >> 4) * 4;
  #pragma unroll
  for (int m = 0; m < 2; ++m)
    #pragma unroll
    for (int r = 0; r < 4; ++r) {
      size_t row = (size_t)(m0 + wr + m * 16 + lq4 + r) * CC + h * DH;
      #pragma unroll
      for (int n = 0; n < 4; ++n)
        ao[row + n * 16 + lr] = f2b(acc[m][n][r]);
    }
}

// ---------------------------------------------------------------------------
// fused final: single global read. Pass1 computes rms AND stores z=pj+qt
// as bf16 into LDS z[c][t] (stride 72). Pass2 reads z rows (b128), scales by
// rms[t]*g[c], coalesced float4 stores to [c][t].
// ---------------------------------------------------------------------------
__global__ __launch_bounds__(256) void final_fused(const short* __restrict__ pj,
                                                   const short* __restrict__ qt,
                                                   const float* __restrict__ g,
                                                   float* __restrict__ out)
{
  __shared__ short z[512 * 72];            // 72 KB
  __shared__ float rmss[64];
  const int t0 = blockIdx.x * 64, b = blockIdx.y;
  const int tid = threadIdx.x;

  {
    const int t = tid >> 2, cb = (tid & 3) * 128;
    const size_t row = ((size_t)b * TT + t0 + t) * CC + cb;
    float ss = 0.f;
    #pragma unroll
    for (int j = 0; j < 16; ++j) {
      bf16x8 a = *(const bf16x8*)(pj + row + j * 8);
      bf16x8 q = *(const bf16x8*)(qt + row + j * 8);
      #pragma unroll
      for (int e = 0; e < 8; ++e) {
        float zf = b2f(a[e]) + b2f(q[e]);
        ss += zf * zf;
        z[(cb + j * 8 + e) * 72 + t] = f2b(zf);
      }
    }
    ss += __shfl_xor(ss, 1);
    ss += __shfl_xor(ss, 2);
    if ((tid & 3) == 0) rmss[t] = rsqrtf(ss * (1.0f / CC) + EPS);
  }
  __syncthreads();

  const int c = tid >> 2, tcs = (tid & 3) * 16;
  #pragma unroll 1
  for (int cb8 = 0; cb8 < 8; ++cb8) {
    const int cc = cb8 * 64 + c;
    const float gc = g[cc];
    bf16x8 z0 = *(const bf16x8*)&z[cc * 72 + tcs];
    bf16x8 z1 = *(const bf16x8*)&z[cc * 72 + tcs + 8];
    float* dst = out + ((size_t)b * CC + cc) * TT + t0 + tcs;
    #pragma unroll
    for (int i = 0; i < 2; ++i) {
      float4 o0 = { b2f(z0[i*4+0]) * rmss[tcs+i*4+0] * gc, b2f(z0[i*4+1]) * rmss[tcs+i*4+1] * gc,
                    b2f(z0[i*4+2]) * rmss[tcs+i*4+2] * gc, b2f(z0[i*4+3]) * rmss[tcs+i*4+3] * gc };
      *(float4*)(dst + i * 4) = o0;
    }
    #pragma unroll
    for (int i = 0; i < 2; ++i) {
      float4 o1 = { b2f(z1[i*4+0]) * rmss[tcs+8+i*4+0] * gc, b2f(z1[i*4+1]) * rmss[tcs+8+i*4+1] * gc,
                    b2f(z1[i*4+2]) * rmss[tcs+8+i*4+2] * gc, b2f(z1[i*4+3]) * rmss[tcs+8+i*4+3] * gc };
      *(float4*)(dst + 8 + i * 4) = o1;
    }
  }
}

// ---------------------------------------------------------------------------
extern "C" void kernel_launch(void* const* d_in, const int* in_sizes, int n_in,
                              void* d_out, int out_size, void* d_ws, size_t ws_size,
                              hipStream_t stream) {
  (void)in_sizes; (void)n_in; (void)out_size; (void)ws_size;
  const float* queries = (const float*)d_in[0];
  const float* keys    = (const float*)d_in[1];
  const float* values  = (const float*)d_in[2];
  const unsigned char* mask = (const unsigned char*)d_in[3];
  const float* Wq = (const float*)d_in[4];
  const float* bq = (const float*)d_in[5];
  const float* gq = (const float*)d_in[6];
  const float* Wk = (const float*)d_in[7];
  const float* bk = (const float*)d_in[8];
  const float* gk = (const float*)d_in[9];
  const float* Wv = (const float*)d_in[10];
  const float* bv = (const float*)d_in[11];
  const float* gv = (const float*)d_in[12];
  const float* Wp = (const float*)d_in[13];
  const float* bp = (const float*)d_in[14];
  const float* g_out = (const float*)d_in[15];

  const size_t NCT = (size_t)NROWS * CC;       // 16,777,216 elements
  short* qt = (short*)d_ws;                    // bf16 [row][c] transposed queries
  short* qf = qt + NCT;                        // feature buffers
  short* kf = qf + NCT;
  short* vf = kf + NCT;
  short* ao = vf + NCT;                        // attention output
  short* pj = ao + NCT;                        // projection output
  float* ctxP = (float*)(pj + NCT);            // 8 x 64 x 4096 fp32
  short* CT  = (short*)(ctxP + (size_t)8 * 64 * DH * DH);   // [bh][v][q] bf16
  short* wqb = CT + (size_t)64 * DH * DH;
  short* wkb = wqb + (size_t)CC * CC;
  short* wvb = wkb + (size_t)CC * CC;
  short* wpb = wvb + (size_t)CC * CC;
  float* S   = (float*)(wpb + (size_t)CC * CC);   // [B][C] softmax sums

  hipMemsetAsync(S, 0, (size_t)BB * CC * sizeof(float), stream);

  conv_w4<<<dim3(CC * CC / 2048, 4), 256, 0, stream>>>(Wq, Wk, Wv, Wp, wqb, wkb, wvb, wpb);

  transpose_cvt1<<<dim3(TT / 256, CC / 64, BB), 256, 0, stream>>>(queries, qt);

  gemm_tc<<<dim3(1024), 256, 0, stream>>>(qt, wqb, bq, qf);

  gemm_direct2<<<dim3(1024, 2), 256, 0, stream>>>(keys, values, wkb, wvb,
                                                  bk, bv, kf, vf);

  feat_all<<<dim3(NROWS / 4, 3), 256, 0, stream>>>(qf, kf, vf, gq, gk, gv, mask);

  ksm_sum<<<dim3(32, BB), 256, 0, stream>>>(kf, S);

  ctx_t<<<dim3(8, BB * HH), 256, 0, stream>>>(kf, vf, ctxP);
  ctx_reduce<<<dim3(64 * DH * DH / 256), 256, 0, stream>>>(ctxP, S, CT);

  attn_t<<<dim3(NROWS / 128, HH), 256, 0, stream>>>(qf, CT, ao);

  gemm_tc<<<dim3(1024), 256, 0, stream>>>(ao, wpb, bp, pj);

  final_fused<<<dim3(TT / 64, BB), 256, 0, stream>>>(pj, qt, g_out, (float*)d_out);
}